// Round 1
// baseline (596.598 us; speedup 1.0000x reference)
//
#include <hip/hip_runtime.h>
#include <hip/hip_bf16.h>

#define B_   2
#define S_   2048
#define H_   16
#define HD_  128
#define D_   2048
#define BS_  4096
#define SCALE_ 0.08838834764831845f   // 1/sqrt(128)

typedef __hip_bfloat16 bf16;
typedef float f32x4 __attribute__((ext_vector_type(4)));
typedef __bf16 bf16x8 __attribute__((ext_vector_type(8)));
typedef unsigned short u16x8 __attribute__((ext_vector_type(8)));

static __device__ __forceinline__ unsigned short f2bf_u(float f) {
  bf16 h = __float2bfloat16(f);
  return __builtin_bit_cast(unsigned short, h);
}
static __device__ __forceinline__ void load_lds16(const void* g, void* l) {
  __builtin_amdgcn_global_load_lds((const __attribute__((address_space(1))) void*)g,
                                   (__attribute__((address_space(3))) void*)l, 16, 0, 0);
}

// ---------------- fp32 -> bf16 convert, 8 elems/thread ----------------
__global__ __launch_bounds__(256) void k_convert(const float* __restrict__ src,
                                                 bf16* __restrict__ dst) {
  const size_t i = ((size_t)blockIdx.x * 256 + threadIdx.x) * 8;
  const float4 a = *(const float4*)(src + i);
  const float4 b = *(const float4*)(src + i + 4);
  u16x8 o;
  o[0] = f2bf_u(a.x); o[1] = f2bf_u(a.y); o[2] = f2bf_u(a.z); o[3] = f2bf_u(a.w);
  o[4] = f2bf_u(b.x); o[5] = f2bf_u(b.y); o[6] = f2bf_u(b.z); o[7] = f2bf_u(b.w);
  *(u16x8*)(dst + i) = o;
}

// ---------- tiled transpose [2048][2048] fp32 -> bf16, one z-slice each ----------
__global__ __launch_bounds__(256) void k_transpose(const float* __restrict__ src0,
                                                   bf16* __restrict__ dst0) {
  const int z = blockIdx.z;
  const float* src = src0 + (size_t)z * D_ * D_;
  bf16* dst = dst0 + (size_t)z * D_ * D_;
  __shared__ float tile[64][65];
  const int t = threadIdx.x;
  const int x0 = blockIdx.x * 64, y0 = blockIdx.y * 64;
#pragma unroll
  for (int i = 0; i < 16; ++i) {
    int idx = t + i * 256, r = idx >> 6, c = idx & 63;
    tile[r][c] = src[(size_t)(y0 + r) * D_ + x0 + c];
  }
  __syncthreads();
#pragma unroll
  for (int i = 0; i < 16; ++i) {
    int idx = t + i * 256, c = idx >> 6, r = idx & 63;
    dst[(size_t)(x0 + c) * D_ + y0 + r] = __float2bfloat16(tile[r][c]);
  }
}

// ---------------- RoPE cos/sin tables [S][64] ----------------
__global__ __launch_bounds__(256) void k_rope_tables(float* __restrict__ cost,
                                                     float* __restrict__ sint) {
  const int idx = blockIdx.x * 256 + threadIdx.x;   // S_*64 total
  const int s = idx >> 6, d = idx & 63;
  const float inv = expf(-(float)d * (9.210340371976184f / 64.f)); // 10000^(-d/64)
  const float ang = (float)s * inv;
  cost[idx] = cosf(ang);
  sint[idx] = sinf(ang);
}

// ---------------- in-place RoPE on q,k ([B,H,S,hd] layout) ----------------
// one wave handles one 128-elem row; lane d handles pair (2d,2d+1) -> (d, d+64)
__global__ __launch_bounds__(256) void k_rope_apply(bf16* __restrict__ qb,
                                                    bf16* __restrict__ kb,
                                                    const float* __restrict__ cost,
                                                    const float* __restrict__ sint) {
  const int rid = blockIdx.x * 4 + (threadIdx.x >> 6);   // (bh, s) row id
  const int lane = threadIdx.x & 63;
  const int s = rid & (S_ - 1);
  const size_t base = (size_t)rid * HD_;
  const float c = cost[s * 64 + lane], sn = sint[s * 64 + lane];
  const float q0 = __bfloat162float(qb[base + 2 * lane]);
  const float q1 = __bfloat162float(qb[base + 2 * lane + 1]);
  const float k0 = __bfloat162float(kb[base + 2 * lane]);
  const float k1 = __bfloat162float(kb[base + 2 * lane + 1]);
  const bf16 qa = __float2bfloat16(q0 * c - q1 * sn);
  const bf16 qc = __float2bfloat16(q0 * sn + q1 * c);
  const bf16 ka = __float2bfloat16(k0 * c - k1 * sn);
  const bf16 kc = __float2bfloat16(k0 * sn + k1 * c);
  qb[base + lane] = qa; qb[base + lane + 64] = qc;
  kb[base + lane] = ka; kb[base + lane + 64] = kc;
}

// ---------------- GEMM core (m97 structure): C[M=4096][128-tile] over K=2048 ----------------
// A [4096][2048] bf16 row-major, Bt [N][2048] bf16 (B transposed).
// MODE 0: QKV epilogue -> qb/kb [B,H,S,hd] bf16 (t=blockIdx.z), v -> vt [B,H,hd,S]
// MODE 1: plain fp32 C [4096][2048] (final output)
template <int MODE>
__global__ __launch_bounds__(256, 2) void k_gemm_bt(const bf16* __restrict__ A,
                                                    const bf16* __restrict__ Bt0,
                                                    float* __restrict__ Cf,
                                                    bf16* __restrict__ qb,
                                                    bf16* __restrict__ kb,
                                                    bf16* __restrict__ vt) {
  const int tid = threadIdx.x;
  const int w = tid >> 6, lane = tid & 63;
  const int wr = w >> 1, wc = w & 1;
  const int lr = lane & 15, lg = lane >> 4;
  const int brow = blockIdx.x * 128, bcol = blockIdx.y * 128;
  const int t = blockIdx.z;
  const bf16* Bt = Bt0 + (size_t)t * D_ * D_;
  __shared__ __align__(16) bf16 As[128 * 32];
  __shared__ __align__(16) bf16 Bs[128 * 32];
  f32x4 acc[4][4] = {};
  for (int k0 = 0; k0 < D_; k0 += 32) {
#pragma unroll
    for (int i = 0; i < 2; ++i) {
      const int slot = i * 256 + tid;
      const int row = slot >> 2, col = (slot & 3) * 8;
      load_lds16(A  + (size_t)(brow + row) * D_ + k0 + col, (char*)As + i * 4096 + w * 1024);
      load_lds16(Bt + (size_t)(bcol + row) * D_ + k0 + col, (char*)Bs + i * 4096 + w * 1024);
    }
    __syncthreads();
    bf16x8 af[4], bfv[4];
#pragma unroll
    for (int m = 0; m < 4; ++m)
      af[m] = *(const bf16x8*)(As + (wr * 64 + m * 16 + lr) * 32 + lg * 8);
#pragma unroll
    for (int n = 0; n < 4; ++n)
      bfv[n] = *(const bf16x8*)(Bs + (wc * 64 + n * 16 + lr) * 32 + lg * 8);
#pragma unroll
    for (int m = 0; m < 4; ++m)
#pragma unroll
      for (int n = 0; n < 4; ++n)
        acc[m][n] = __builtin_amdgcn_mfma_f32_16x16x32_bf16(af[m], bfv[n], acc[m][n], 0, 0, 0);
    __syncthreads();
  }
  if (MODE == 1) {
#pragma unroll
    for (int m = 0; m < 4; ++m)
#pragma unroll
      for (int n = 0; n < 4; ++n)
#pragma unroll
        for (int j = 0; j < 4; ++j) {
          const int row = brow + wr * 64 + m * 16 + lg * 4 + j;
          const int col = bcol + wc * 64 + n * 16 + lr;
          Cf[(size_t)row * D_ + col] = acc[m][n][j];
        }
  } else {
#pragma unroll
    for (int m = 0; m < 4; ++m)
#pragma unroll
      for (int n = 0; n < 4; ++n)
#pragma unroll
        for (int j = 0; j < 4; ++j) {
          const int row = brow + wr * 64 + m * 16 + lg * 4 + j;  // (b,s)
          const int col = bcol + wc * 64 + n * 16 + lr;          // (h,m)
          const int b = row >> 11, s = row & (S_ - 1);
          const int h = col >> 7, mm = col & (HD_ - 1);
          const bf16 val = __float2bfloat16(acc[m][n][j]);
          if (t == 2)
            vt[((size_t)(b * H_ + h) * HD_ + mm) * S_ + s] = val;
          else if (t == 1)
            kb[((size_t)(b * H_ + h) * S_ + s) * HD_ + mm] = val;
          else
            qb[((size_t)(b * H_ + h) * S_ + s) * HD_ + mm] = val;
        }
  }
}

// ---------------- flash attention (causal + key-padding mask, diag forced on) ----------------
// grid (S/64, B*H); 4 waves x 16 q-rows. K staged to LDS with XOR swizzle; V read from vt global.
__global__ __launch_bounds__(256, 2) void k_attn(const bf16* __restrict__ qb,
                                                 const bf16* __restrict__ kb,
                                                 const bf16* __restrict__ vt,
                                                 const int* __restrict__ mask,
                                                 bf16* __restrict__ attn_b) {
  const int tid = threadIdx.x, w = tid >> 6, lane = tid & 63;
  const int lr = lane & 15, lg = lane >> 4;
  const int q0 = blockIdx.x * 64;
  const int bh = blockIdx.y;
  const int b = bh >> 4, h = bh & (H_ - 1);
  const bf16* qp = qb + (size_t)bh * S_ * HD_;
  const bf16* kp = kb + (size_t)bh * S_ * HD_;
  const bf16* vp = vt + (size_t)bh * HD_ * S_;
  __shared__ __align__(16) bf16 Ks[64 * 128];     // swizzled K tile (16 KB)
  __shared__ __align__(16) bf16 Ps[4][16][72];    // per-wave P tile, +16B pad

  const int qrow = q0 + w * 16 + lr;
  bf16x8 qf[4];
#pragma unroll
  for (int ks = 0; ks < 4; ++ks)
    qf[ks] = *(const bf16x8*)(qp + (size_t)qrow * HD_ + ks * 32 + lg * 8);

  float m_run[4], l_run[4];
  f32x4 oacc[8];
#pragma unroll
  for (int j = 0; j < 4; ++j) { m_run[j] = -INFINITY; l_run[j] = 0.f; }
#pragma unroll
  for (int c = 0; c < 8; ++c) oacc[c] = (f32x4)(0.f);

  const int kv_end = q0 + 64;
  for (int k0 = 0; k0 < kv_end; k0 += 64) {
    // stage K block [64][128], XOR-swizzled source so reads are conflict-free
#pragma unroll
    for (int i = 0; i < 4; ++i) {
      const int slot = i * 256 + tid;
      const int row = slot >> 4, j16 = slot & 15;
      const bf16* src = kp + (size_t)(k0 + row) * HD_ + ((j16 ^ (row & 7)) * 8);
      load_lds16(src, (char*)Ks + i * 4096 + w * 1024);
    }
    __syncthreads();

    // scores: QK^T (16q x 64k per wave)
    f32x4 sacc[4] = {};
#pragma unroll
    for (int n = 0; n < 4; ++n) {
      const int krow = n * 16 + lr;
#pragma unroll
      for (int ks = 0; ks < 4; ++ks) {
        const int j16 = (ks * 4 + lg) ^ (krow & 7);
        const bf16x8 kf = *(const bf16x8*)(Ks + krow * 128 + j16 * 8);
        sacc[n] = __builtin_amdgcn_mfma_f32_16x16x32_bf16(qf[ks], kf, sacc[n], 0, 0, 0);
      }
    }

    // scale + mask
    float mblk[4] = {-INFINITY, -INFINITY, -INFINITY, -INFINITY};
#pragma unroll
    for (int n = 0; n < 4; ++n) {
      const int kcol = k0 + n * 16 + lr;
      const int mk = mask[b * S_ + kcol];
#pragma unroll
      for (int j = 0; j < 4; ++j) {
        const int r = q0 + w * 16 + lg * 4 + j;
        float sv = sacc[n][j] * SCALE_;
        const bool allowed = (kcol <= r) && (mk != 0 || kcol == r);
        sv = allowed ? sv : -1e9f;
        sacc[n][j] = sv;
        mblk[j] = fmaxf(mblk[j], sv);
      }
    }
#pragma unroll
    for (int xm = 1; xm < 16; xm <<= 1)
#pragma unroll
      for (int j = 0; j < 4; ++j)
        mblk[j] = fmaxf(mblk[j], __shfl_xor(mblk[j], xm, 64));

    // online softmax update
    float alpha[4], psum[4];
#pragma unroll
    for (int j = 0; j < 4; ++j) {
      const float mn = fmaxf(m_run[j], mblk[j]);
      alpha[j] = __expf(m_run[j] - mn);
      m_run[j] = mn;
      psum[j] = 0.f;
    }
#pragma unroll
    for (int n = 0; n < 4; ++n)
#pragma unroll
      for (int j = 0; j < 4; ++j) {
        const float p = __expf(sacc[n][j] - m_run[j]);
        psum[j] += p;
        sacc[n][j] = p;
      }
#pragma unroll
    for (int xm = 1; xm < 16; xm <<= 1)
#pragma unroll
      for (int j = 0; j < 4; ++j)
        psum[j] += __shfl_xor(psum[j], xm, 64);
#pragma unroll
    for (int j = 0; j < 4; ++j) l_run[j] = l_run[j] * alpha[j] + psum[j];

    // P -> LDS (bf16), per-wave private tile
#pragma unroll
    for (int n = 0; n < 4; ++n)
#pragma unroll
      for (int j = 0; j < 4; ++j)
        Ps[w][lg * 4 + j][n * 16 + lr] = __float2bfloat16(sacc[n][j]);

    // rescale O
#pragma unroll
    for (int c = 0; c < 8; ++c)
#pragma unroll
      for (int j = 0; j < 4; ++j) oacc[c][j] *= alpha[j];

    // PV: A = P (from LDS), B = V^T fragments direct from global vt
    bf16x8 pa[2];
#pragma unroll
    for (int ks = 0; ks < 2; ++ks)
      pa[ks] = *(const bf16x8*)(&Ps[w][lr][ks * 32 + lg * 8]);
#pragma unroll
    for (int c = 0; c < 8; ++c) {
#pragma unroll
      for (int ks = 0; ks < 2; ++ks) {
        const bf16x8 vf = *(const bf16x8*)(vp + (size_t)(c * 16 + lr) * S_ + k0 + ks * 32 + lg * 8);
        oacc[c] = __builtin_amdgcn_mfma_f32_16x16x32_bf16(pa[ks], vf, oacc[c], 0, 0, 0);
      }
    }
    __syncthreads();
  }

  // epilogue: normalize and write attn_b [B,S,H*hd] bf16
#pragma unroll
  for (int j = 0; j < 4; ++j) {
    const float inv = 1.f / l_run[j];
    const int r = q0 + w * 16 + lg * 4 + j;
#pragma unroll
    for (int c = 0; c < 8; ++c)
      attn_b[(size_t)(b * S_ + r) * D_ + h * HD_ + c * 16 + lr] =
          __float2bfloat16(oacc[c][j] * inv);
  }
}

extern "C" void kernel_launch(void* const* d_in, const int* in_sizes, int n_in,
                              void* d_out, int out_size, void* d_ws, size_t ws_size,
                              hipStream_t stream) {
  (void)in_sizes; (void)n_in; (void)out_size; (void)ws_size;
  const float* x        = (const float*)d_in[0];
  const int*   attn_mask= (const int*)d_in[1];
  const float* in_proj  = (const float*)d_in[2];
  const float* out_proj = (const float*)d_in[3];
  float* out = (float*)d_out;
  char* ws = (char*)d_ws;

  // workspace layout (bytes)
  bf16*  xb    = (bf16*)(ws + 0);            // 16,777,216  (also attn_b later)
  bf16*  wqkvT = (bf16*)(ws + 16777216);     // 25,165,824
  bf16*  woT   = (bf16*)(ws + 41943040);     //  8,388,608
  float* cost  = (float*)(ws + 50331648);    //    524,288
  float* sint  = (float*)(ws + 50855936);    //    524,288
  bf16*  vt    = (bf16*)(ws + 51380224);     // 16,777,216  -> total 68,157,440
  // q,k live in d_out as scratch (dead before final GEMM overwrites d_out)
  bf16* qb = (bf16*)d_out;
  bf16* kb = (bf16*)((char*)d_out + 16777216);
  bf16* attn_b = xb;  // xb dead after QKV GEMM

  k_convert<<<4096, 256, 0, stream>>>(x, xb);
  k_transpose<<<dim3(32, 32, 3), 256, 0, stream>>>(in_proj, wqkvT);
  k_transpose<<<dim3(32, 32, 1), 256, 0, stream>>>(out_proj, woT);
  k_rope_tables<<<512, 256, 0, stream>>>(cost, sint);
  k_gemm_bt<0><<<dim3(32, 16, 3), 256, 0, stream>>>(xb, wqkvT, nullptr, qb, kb, vt);
  k_rope_apply<<<16384, 256, 0, stream>>>(qb, kb, cost, sint);
  k_attn<<<dim3(32, 32), 256, 0, stream>>>(qb, kb, vt, attn_mask, attn_b);
  k_gemm_bt<1><<<dim3(32, 16, 1), 256, 0, stream>>>(attn_b, woT, out, nullptr, nullptr, nullptr);
}

// Round 2
// 386.522 us; speedup vs baseline: 1.5435x; 1.5435x over previous
//
#include <hip/hip_runtime.h>
#include <hip/hip_bf16.h>

#define B_   2
#define S_   2048
#define H_   16
#define HD_  128
#define D_   2048
#define BS_  4096
#define SCALE_ 0.08838834764831845f   // 1/sqrt(128)

typedef __hip_bfloat16 bf16;
typedef float f32x4 __attribute__((ext_vector_type(4)));
typedef __bf16 bf16x8 __attribute__((ext_vector_type(8)));
typedef unsigned short u16x8 __attribute__((ext_vector_type(8)));

static __device__ __forceinline__ unsigned short f2bf_u(float f) {
  bf16 h = __float2bfloat16(f);
  return __builtin_bit_cast(unsigned short, h);
}
static __device__ __forceinline__ void load_lds16(const void* g, void* l) {
  __builtin_amdgcn_global_load_lds((const __attribute__((address_space(1))) void*)g,
                                   (__attribute__((address_space(3))) void*)l, 16, 0, 0);
}

// ---------------- fp32 -> bf16 convert, 8 elems/thread ----------------
__global__ __launch_bounds__(256) void k_convert(const float* __restrict__ src,
                                                 bf16* __restrict__ dst) {
  const size_t i = ((size_t)blockIdx.x * 256 + threadIdx.x) * 8;
  const float4 a = *(const float4*)(src + i);
  const float4 b = *(const float4*)(src + i + 4);
  u16x8 o;
  o[0] = f2bf_u(a.x); o[1] = f2bf_u(a.y); o[2] = f2bf_u(a.z); o[3] = f2bf_u(a.w);
  o[4] = f2bf_u(b.x); o[5] = f2bf_u(b.y); o[6] = f2bf_u(b.z); o[7] = f2bf_u(b.w);
  *(u16x8*)(dst + i) = o;
}

// ---------- tiled transpose [2048][2048] fp32 -> bf16, one z-slice each ----------
__global__ __launch_bounds__(256) void k_transpose(const float* __restrict__ src0,
                                                   bf16* __restrict__ dst0) {
  const int z = blockIdx.z;
  const float* src = src0 + (size_t)z * D_ * D_;
  bf16* dst = dst0 + (size_t)z * D_ * D_;
  __shared__ float tile[64][65];
  const int t = threadIdx.x;
  const int x0 = blockIdx.x * 64, y0 = blockIdx.y * 64;
#pragma unroll
  for (int i = 0; i < 16; ++i) {
    int idx = t + i * 256, r = idx >> 6, c = idx & 63;
    tile[r][c] = src[(size_t)(y0 + r) * D_ + x0 + c];
  }
  __syncthreads();
#pragma unroll
  for (int i = 0; i < 16; ++i) {
    int idx = t + i * 256, c = idx >> 6, r = idx & 63;
    dst[(size_t)(x0 + c) * D_ + y0 + r] = __float2bfloat16(tile[r][c]);
  }
}

// ---------------- RoPE cos/sin tables [S][64] ----------------
__global__ __launch_bounds__(256) void k_rope_tables(float* __restrict__ cost,
                                                     float* __restrict__ sint) {
  const int idx = blockIdx.x * 256 + threadIdx.x;   // S_*64 total
  const int s = idx >> 6, d = idx & 63;
  const float inv = expf(-(float)d * (9.210340371976184f / 64.f)); // 10000^(-d/64)
  const float ang = (float)s * inv;
  cost[idx] = cosf(ang);
  sint[idx] = sinf(ang);
}

// ---------------- in-place RoPE on q,k ([B,H,S,hd] layout) ----------------
__global__ __launch_bounds__(256) void k_rope_apply(bf16* __restrict__ qb,
                                                    bf16* __restrict__ kb,
                                                    const float* __restrict__ cost,
                                                    const float* __restrict__ sint) {
  const int rid = blockIdx.x * 4 + (threadIdx.x >> 6);   // (bh, s) row id
  const int lane = threadIdx.x & 63;
  const int s = rid & (S_ - 1);
  const size_t base = (size_t)rid * HD_;
  const float c = cost[s * 64 + lane], sn = sint[s * 64 + lane];
  const float q0 = __bfloat162float(qb[base + 2 * lane]);
  const float q1 = __bfloat162float(qb[base + 2 * lane + 1]);
  const float k0 = __bfloat162float(kb[base + 2 * lane]);
  const float k1 = __bfloat162float(kb[base + 2 * lane + 1]);
  const bf16 qa = __float2bfloat16(q0 * c - q1 * sn);
  const bf16 qc = __float2bfloat16(q0 * sn + q1 * c);
  const bf16 ka = __float2bfloat16(k0 * c - k1 * sn);
  const bf16 kc = __float2bfloat16(k0 * sn + k1 * c);
  qb[base + lane] = qa; qb[base + lane + 64] = qc;
  kb[base + lane] = ka; kb[base + lane + 64] = kc;
}

// ---------------- GEMM core (m97 structure) ----------------
template <int MODE>
__global__ __launch_bounds__(256, 2) void k_gemm_bt(const bf16* __restrict__ A,
                                                    const bf16* __restrict__ Bt0,
                                                    float* __restrict__ Cf,
                                                    bf16* __restrict__ qb,
                                                    bf16* __restrict__ kb,
                                                    bf16* __restrict__ vt) {
  const int tid = threadIdx.x;
  const int w = tid >> 6, lane = tid & 63;
  const int wr = w >> 1, wc = w & 1;
  const int lr = lane & 15, lg = lane >> 4;
  const int brow = blockIdx.x * 128, bcol = blockIdx.y * 128;
  const int t = blockIdx.z;
  const bf16* Bt = Bt0 + (size_t)t * D_ * D_;
  __shared__ __align__(16) bf16 As[128 * 32];
  __shared__ __align__(16) bf16 Bs[128 * 32];
  f32x4 acc[4][4] = {};
  for (int k0 = 0; k0 < D_; k0 += 32) {
#pragma unroll
    for (int i = 0; i < 2; ++i) {
      const int slot = i * 256 + tid;
      const int row = slot >> 2, col = (slot & 3) * 8;
      load_lds16(A  + (size_t)(brow + row) * D_ + k0 + col, (char*)As + i * 4096 + w * 1024);
      load_lds16(Bt + (size_t)(bcol + row) * D_ + k0 + col, (char*)Bs + i * 4096 + w * 1024);
    }
    __syncthreads();
    bf16x8 af[4], bfv[4];
#pragma unroll
    for (int m = 0; m < 4; ++m)
      af[m] = *(const bf16x8*)(As + (wr * 64 + m * 16 + lr) * 32 + lg * 8);
#pragma unroll
    for (int n = 0; n < 4; ++n)
      bfv[n] = *(const bf16x8*)(Bs + (wc * 64 + n * 16 + lr) * 32 + lg * 8);
#pragma unroll
    for (int m = 0; m < 4; ++m)
#pragma unroll
      for (int n = 0; n < 4; ++n)
        acc[m][n] = __builtin_amdgcn_mfma_f32_16x16x32_bf16(af[m], bfv[n], acc[m][n], 0, 0, 0);
    __syncthreads();
  }
  if (MODE == 1) {
#pragma unroll
    for (int m = 0; m < 4; ++m)
#pragma unroll
      for (int n = 0; n < 4; ++n)
#pragma unroll
        for (int j = 0; j < 4; ++j) {
          const int row = brow + wr * 64 + m * 16 + lg * 4 + j;
          const int col = bcol + wc * 64 + n * 16 + lr;
          Cf[(size_t)row * D_ + col] = acc[m][n][j];
        }
  } else {
#pragma unroll
    for (int m = 0; m < 4; ++m)
#pragma unroll
      for (int n = 0; n < 4; ++n)
#pragma unroll
        for (int j = 0; j < 4; ++j) {
          const int row = brow + wr * 64 + m * 16 + lg * 4 + j;  // (b,s)
          const int col = bcol + wc * 64 + n * 16 + lr;          // (h,m)
          const int b = row >> 11, s = row & (S_ - 1);
          const int h = col >> 7, mm = col & (HD_ - 1);
          const bf16 val = __float2bfloat16(acc[m][n][j]);
          if (t == 2)
            vt[((size_t)(b * H_ + h) * HD_ + mm) * S_ + s] = val;
          else if (t == 1)
            kb[((size_t)(b * H_ + h) * S_ + s) * HD_ + mm] = val;
          else
            qb[((size_t)(b * H_ + h) * S_ + s) * HD_ + mm] = val;
        }
  }
}

// ---------------- flash attention: K+V in LDS, double-buffered 2-phase ----------------
// grid (32, B*H); heavy q-tiles launch first. 4 waves x 16 q-rows.
__global__ __launch_bounds__(256, 2) void k_attn(const bf16* __restrict__ qb,
                                                 const bf16* __restrict__ kb,
                                                 const bf16* __restrict__ vt,
                                                 const int* __restrict__ mask,
                                                 bf16* __restrict__ attn_b) {
  const int tid = threadIdx.x, w = tid >> 6, lane = tid & 63;
  const int lr = lane & 15, lg = lane >> 4;
  const int qt = gridDim.x - 1 - blockIdx.x;      // heavy tiles first
  const int q0 = qt * 64;
  const int bh = blockIdx.y;
  const int b = bh >> 4, h = bh & (H_ - 1);
  const bf16* qp = qb + (size_t)bh * S_ * HD_;
  const bf16* kp = kb + (size_t)bh * S_ * HD_;
  const bf16* vp = vt + (size_t)bh * HD_ * S_;
  __shared__ __align__(16) bf16 Ks[2][64 * 128];   // 2 x 16 KB, XOR-swizzled rows
  __shared__ __align__(16) bf16 Vs[2][128 * 64];   // 2 x 16 KB, XOR-swizzled rows
  __shared__ __align__(16) bf16 Ps[4][16][72];     // per-wave P tile, padded

  // Q fragments (rows q0 + w*16 + lr)
  const int qrow = q0 + w * 16 + lr;
  bf16x8 qf[4];
#pragma unroll
  for (int ks = 0; ks < 4; ++ks)
    qf[ks] = *(const bf16x8*)(qp + (size_t)qrow * HD_ + ks * 32 + lg * 8);

  float m_run[4], l_run[4];
  f32x4 oacc[8];
#pragma unroll
  for (int j = 0; j < 4; ++j) { m_run[j] = -INFINITY; l_run[j] = 0.f; }
#pragma unroll
  for (int c = 0; c < 8; ++c) oacc[c] = (f32x4)(0.f);

  // stage K[64][128] and V[128][64] for tile k0 into buffer buf.
  // sources pre-swizzled (unit ^= row&7 on 16B units) so linear LDS dest + swizzled reads match.
  auto stage = [&](int buf, int k0) {
#pragma unroll
    for (int i = 0; i < 4; ++i) {
      const int slot = i * 256 + tid;
      const int row = slot >> 4, j16 = slot & 15;
      load_lds16(kp + (size_t)(k0 + row) * HD_ + ((j16 ^ (row & 7)) * 8),
                 (char*)&Ks[buf][0] + i * 4096 + w * 1024);
    }
#pragma unroll
    for (int i = 0; i < 4; ++i) {
      const int slot = i * 256 + tid;
      const int row = slot >> 3, j8 = slot & 7;
      load_lds16(vp + (size_t)row * S_ + k0 + ((j8 ^ (row & 7)) * 8),
                 (char*)&Vs[buf][0] + i * 4096 + w * 1024);
    }
  };

  const int nt = qt + 1;
  stage(0, 0);
  asm volatile("s_waitcnt vmcnt(0)" ::: "memory");
  __syncthreads();

  int cur = 0;
  for (int it = 0; it < nt; ++it) {
    const int k0 = it * 64;
    if (it + 1 < nt) stage(cur ^ 1, k0 + 64);   // prefetch next tile (stays in flight)

    // hoist mask loads (used after the MFMA cluster)
    int mk4[4];
#pragma unroll
    for (int n = 0; n < 4; ++n) mk4[n] = mask[b * S_ + k0 + n * 16 + lr];

    const bf16* ksb = &Ks[cur][0];
    const bf16* vsb = &Vs[cur][0];

    // QK^T: 16q x 64k per wave
    f32x4 sacc[4] = {};
#pragma unroll
    for (int n = 0; n < 4; ++n) {
      const int krow = n * 16 + lr;
#pragma unroll
      for (int ks = 0; ks < 4; ++ks) {
        const int j16 = (ks * 4 + lg) ^ (krow & 7);
        const bf16x8 kf = *(const bf16x8*)(ksb + krow * 128 + j16 * 8);
        sacc[n] = __builtin_amdgcn_mfma_f32_16x16x32_bf16(qf[ks], kf, sacc[n], 0, 0, 0);
      }
    }

    // scale + mask
    float mblk[4] = {-INFINITY, -INFINITY, -INFINITY, -INFINITY};
#pragma unroll
    for (int n = 0; n < 4; ++n) {
      const int kcol = k0 + n * 16 + lr;
#pragma unroll
      for (int j = 0; j < 4; ++j) {
        const int r = q0 + w * 16 + lg * 4 + j;
        float sv = sacc[n][j] * SCALE_;
        const bool allowed = (kcol <= r) && (mk4[n] != 0 || kcol == r);
        sv = allowed ? sv : -1e9f;
        sacc[n][j] = sv;
        mblk[j] = fmaxf(mblk[j], sv);
      }
    }
#pragma unroll
    for (int xm = 1; xm < 16; xm <<= 1)
#pragma unroll
      for (int j = 0; j < 4; ++j)
        mblk[j] = fmaxf(mblk[j], __shfl_xor(mblk[j], xm, 64));

    // online softmax update
    float alpha[4], psum[4];
#pragma unroll
    for (int j = 0; j < 4; ++j) {
      const float mn = fmaxf(m_run[j], mblk[j]);
      alpha[j] = __expf(m_run[j] - mn);
      m_run[j] = mn;
      psum[j] = 0.f;
    }
#pragma unroll
    for (int n = 0; n < 4; ++n)
#pragma unroll
      for (int j = 0; j < 4; ++j) {
        const float p = __expf(sacc[n][j] - m_run[j]);
        psum[j] += p;
        sacc[n][j] = p;
      }
#pragma unroll
    for (int xm = 1; xm < 16; xm <<= 1)
#pragma unroll
      for (int j = 0; j < 4; ++j)
        psum[j] += __shfl_xor(psum[j], xm, 64);
#pragma unroll
    for (int j = 0; j < 4; ++j) l_run[j] = l_run[j] * alpha[j] + psum[j];

    // P -> LDS (per-wave private tile)
#pragma unroll
    for (int n = 0; n < 4; ++n)
#pragma unroll
      for (int j = 0; j < 4; ++j)
        Ps[w][lg * 4 + j][n * 16 + lr] = __float2bfloat16(sacc[n][j]);

    // rescale O
#pragma unroll
    for (int c = 0; c < 8; ++c)
#pragma unroll
      for (int j = 0; j < 4; ++j) oacc[c][j] *= alpha[j];

    // PV: A = P (LDS), B = V^T fragments from swizzled LDS
    bf16x8 pa[2];
#pragma unroll
    for (int ks = 0; ks < 2; ++ks)
      pa[ks] = *(const bf16x8*)(&Ps[w][lr][ks * 32 + lg * 8]);
#pragma unroll
    for (int c = 0; c < 8; ++c) {
#pragma unroll
      for (int ks = 0; ks < 2; ++ks) {
        const int vrow = c * 16 + lr;
        const int unit = (ks * 4 + lg) ^ (vrow & 7);
        const bf16x8 vf = *(const bf16x8*)(vsb + vrow * 64 + unit * 8);
        oacc[c] = __builtin_amdgcn_mfma_f32_16x16x32_bf16(pa[ks], vf, oacc[c], 0, 0, 0);
      }
    }

    asm volatile("s_waitcnt vmcnt(0)" ::: "memory");  // next tile staged
    __syncthreads();                                   // all waves done with cur
    cur ^= 1;
  }

  // epilogue: normalize and write attn_b [B,S,H*hd] bf16
#pragma unroll
  for (int j = 0; j < 4; ++j) {
    const float inv = 1.f / l_run[j];
    const int r = q0 + w * 16 + lg * 4 + j;
#pragma unroll
    for (int c = 0; c < 8; ++c)
      attn_b[(size_t)(b * S_ + r) * D_ + h * HD_ + c * 16 + lr] =
          __float2bfloat16(oacc[c][j] * inv);
  }
}

extern "C" void kernel_launch(void* const* d_in, const int* in_sizes, int n_in,
                              void* d_out, int out_size, void* d_ws, size_t ws_size,
                              hipStream_t stream) {
  (void)in_sizes; (void)n_in; (void)out_size; (void)ws_size;
  const float* x        = (const float*)d_in[0];
  const int*   attn_mask= (const int*)d_in[1];
  const float* in_proj  = (const float*)d_in[2];
  const float* out_proj = (const float*)d_in[3];
  float* out = (float*)d_out;
  char* ws = (char*)d_ws;

  bf16*  xb    = (bf16*)(ws + 0);            // 16 MB (also attn_b later)
  bf16*  wqkvT = (bf16*)(ws + 16777216);     // 24 MB
  bf16*  woT   = (bf16*)(ws + 41943040);     //  8 MB
  float* cost  = (float*)(ws + 50331648);
  float* sint  = (float*)(ws + 50855936);
  bf16*  vt    = (bf16*)(ws + 51380224);     // 16 MB
  bf16* qb = (bf16*)d_out;                   // d_out as scratch (dead before final GEMM)
  bf16* kb = (bf16*)((char*)d_out + 16777216);
  bf16* attn_b = xb;

  k_convert<<<4096, 256, 0, stream>>>(x, xb);
  k_transpose<<<dim3(32, 32, 3), 256, 0, stream>>>(in_proj, wqkvT);
  k_transpose<<<dim3(32, 32, 1), 256, 0, stream>>>(out_proj, woT);
  k_rope_tables<<<512, 256, 0, stream>>>(cost, sint);
  k_gemm_bt<0><<<dim3(32, 16, 3), 256, 0, stream>>>(xb, wqkvT, nullptr, qb, kb, vt);
  k_rope_apply<<<16384, 256, 0, stream>>>(qb, kb, cost, sint);
  k_attn<<<dim3(32, 32), 256, 0, stream>>>(qb, kb, vt, attn_mask, attn_b);
  k_gemm_bt<1><<<dim3(32, 16, 1), 256, 0, stream>>>(attn_b, woT, out, nullptr, nullptr, nullptr);
}